// Round 6
// baseline (63.165 us; speedup 1.0000x reference)
//
#include <hip/hip_runtime.h>

#define DD 128
#define KADJ 12
#define BN_TOTAL 12800

typedef float f32x4 __attribute__((ext_vector_type(4)));
typedef float f32x2 __attribute__((ext_vector_type(2)));
typedef __bf16 bf16x8 __attribute__((ext_vector_type(8)));
typedef __bf16 bf16x2 __attribute__((ext_vector_type(2)));
typedef unsigned int u32;

__device__ __forceinline__ bf16x8 cvt8(f32x4 a, f32x4 b) {
    bf16x8 r;
    r[0] = (__bf16)a[0]; r[1] = (__bf16)a[1]; r[2] = (__bf16)a[2]; r[3] = (__bf16)a[3];
    r[4] = (__bf16)b[0]; r[5] = (__bf16)b[1]; r[6] = (__bf16)b[2]; r[7] = (__bf16)b[3];
    return r;
}

__device__ __forceinline__ bf16x8 mul8(bf16x8 a, bf16x8 b) {
    bf16x8 r;
    #pragma unroll
    for (int i = 0; i < 8; ++i) r[i] = (__bf16)((float)a[i] * (float)b[i]);
    return r;
}

// ---- K0: shuffle w1 (rows 0..127) and w3 into MFMA B-fragment order, bf16 ----
__global__ void k_prep(const float* __restrict__ w1, const float* __restrict__ w3,
                       __bf16* __restrict__ w1f, __bf16* __restrict__ w3f) {
    int idx = blockIdx.x * 256 + threadIdx.x;   // 0..49151
    int lane = (idx >> 3) & 63, e = idx & 7;
    int l = lane & 15, gg = lane >> 4;
    if (idx < 16384) {
        int fi = idx >> 9, n = fi >> 2, ks = fi & 3;
        int k = ks * 32 + gg * 8 + e;
        w1f[idx] = (__bf16)w1[k * DD + n * 16 + l];
    } else {
        int j = idx - 16384;
        int fi = j >> 9, n = fi >> 3, ks = fi & 7;
        int k = ks * 32 + gg * 8 + e;
        w3f[j] = (__bf16)w3[k * DD + n * 16 + l];
    }
}

// ---- K1: B-frags in 128 VGPRs (loaded once/wave); 8 bn per wave; wave-local LDS,
// ---- zero barriers; register prefetch of next bn's adj/ave/wgt. ----
__launch_bounds__(256, 2)
__global__ void k_att(const float* __restrict__ ave, const float* __restrict__ adj,
                      const float* __restrict__ wgt, const float* __restrict__ w1,
                      const float* __restrict__ w2, const __bf16* __restrict__ w1f,
                      float* __restrict__ att_out) {
    __shared__ unsigned char lds[4 * 3344];     // per wave: 12x256B adj + 272B ave
    const int t = threadIdx.x;
    const int lane = t & 63;
    const int w = t >> 6;
    const int l = lane & 15, g = lane >> 4;
    const int bn0 = (blockIdx.x * 4 + w) * 8;

    unsigned char* adjb = lds + w * 3344;
    unsigned char* aveb = adjb + 3072;

    // ---- B fragments: whole w1 in registers, coalesced 1KB wave loads ----
    bf16x8 bfr[4][8];
    #pragma unroll
    for (int ks = 0; ks < 4; ++ks)
        #pragma unroll
        for (int n = 0; n < 8; ++n)
            bfr[ks][n] = *reinterpret_cast<const bf16x8*>(
                w1f + ((size_t)(n * 4 + ks) * 512 + lane * 8));

    // loop-invariant epilogue operands
    float w1r[8], w2v[8];
    #pragma unroll
    for (int n = 0; n < 8; ++n) {
        w1r[n] = w1[128 * DD + n * 16 + l];   // w1 row 128 = concat'd wgt row
        w2v[n] = w2[n * 16 + l];
    }

    // ---- register prefetch buffers ----
    f32x4 pa[6]; f32x2 pv; f32x4 pw;
    #define ISSUE(BN) do {                                                        \
        const float* gs_ = adj + (size_t)(BN) * (KADJ * DD);                      \
        _Pragma("unroll")                                                         \
        for (int i_ = 0; i_ < 3; ++i_) {                                          \
            int row_ = i_ * 4 + g;                                                \
            pa[2*i_]   = __builtin_nontemporal_load(                              \
                reinterpret_cast<const f32x4*>(gs_ + row_ * DD + l * 8));         \
            pa[2*i_+1] = __builtin_nontemporal_load(                              \
                reinterpret_cast<const f32x4*>(gs_ + row_ * DD + l * 8 + 4));     \
        }                                                                         \
        pv = *reinterpret_cast<const f32x2*>(ave + (size_t)(BN) * DD + lane * 2); \
        pw = (g < 3) ? *reinterpret_cast<const f32x4*>(wgt + (size_t)(BN) * KADJ + g * 4) \
                     : f32x4{0.f, 0.f, 0.f, 0.f};                                 \
    } while (0)

    ISSUE(bn0);

    for (int it = 0; it < 8; ++it) {
        const int bn = bn0 + it;

        // ---- stage prefetched regs -> wave-local LDS (swizzled) ----
        #pragma unroll
        for (int i = 0; i < 3; ++i) {
            int row = i * 4 + g;
            *reinterpret_cast<bf16x8*>(adjb + row * 256 + ((l ^ row) << 4)) =
                cvt8(pa[2 * i], pa[2 * i + 1]);
        }
        {
            bf16x2 bv; bv[0] = (__bf16)pv[0]; bv[1] = (__bf16)pv[1];
            *reinterpret_cast<bf16x2*>(aveb + lane * 4) = bv;
        }
        f32x4 wvv = pw;

        // ---- issue next bn's global loads now; they complete under this compute ----
        if (it < 7) ISSUE(bn + 1);

        // ---- MFMA: C[16x128] = (ave*adj) @ w1^T, B from registers ----
        const int l2 = l < KADJ ? l : KADJ - 1;
        f32x4 acc[8];
        #pragma unroll
        for (int n = 0; n < 8; ++n) acc[n] = f32x4{0.f, 0.f, 0.f, 0.f};
        #pragma unroll
        for (int ks = 0; ks < 4; ++ks) {
            bf16x8 adjf = *reinterpret_cast<const bf16x8*>(
                adjb + l2 * 256 + (((ks * 4 + g) ^ l2) << 4));
            bf16x8 avef = *reinterpret_cast<const bf16x8*>(aveb + ks * 64 + g * 16);
            bf16x8 af = mul8(adjf, avef);
            #pragma unroll
            for (int n = 0; n < 8; ++n)
                acc[n] = __builtin_amdgcn_mfma_f32_16x16x32_bf16(af, bfr[ks][n], acc[n], 0, 0, 0);
        }

        // ---- epilogue: rank-1 wgt col, leaky, dot w2; reduce over 16 l-lanes ----
        float p[4] = {0.f, 0.f, 0.f, 0.f};
        #pragma unroll
        for (int n = 0; n < 8; ++n) {
            #pragma unroll
            for (int j = 0; j < 4; ++j) {
                float h = fmaf(wvv[j], w1r[n], acc[n][j]);
                h = h > 0.f ? h : 0.2f * h;
                p[j] = fmaf(h, w2v[n], p[j]);
            }
        }
        #pragma unroll
        for (int j = 0; j < 4; ++j) {
            p[j] += __shfl_xor(p[j], 1, 64);
            p[j] += __shfl_xor(p[j], 2, 64);
            p[j] += __shfl_xor(p[j], 4, 64);
            p[j] += __shfl_xor(p[j], 8, 64);
            if (g == 3) p[j] = -1e30f;        // pad rows 12..15 out of softmax
        }

        // gather all 16 scores; softmax stats
        float q0[4], q1[4], q2[4];
        #pragma unroll
        for (int j = 0; j < 4; ++j) {
            q0[j] = __shfl_xor(p[j], 16, 64);
            q1[j] = __shfl_xor(p[j], 32, 64);
            q2[j] = __shfl_xor(q1[j], 16, 64);
        }
        float mx = -1e30f;
        #pragma unroll
        for (int j = 0; j < 4; ++j)
            mx = fmaxf(mx, fmaxf(fmaxf(p[j], q0[j]), fmaxf(q1[j], q2[j])));
        float ssum = 0.f;
        #pragma unroll
        for (int j = 0; j < 4; ++j) {
            ssum += __expf(p[j] - mx);  ssum += __expf(q0[j] - mx);
            ssum += __expf(q1[j] - mx); ssum += __expf(q2[j] - mx);
        }
        float inv = 1.f / ssum;

        // ---- att: lanes = column pairs, adj columns from swizzled LDS ----
        float a0 = 0.f, a1 = 0.f;
        #pragma unroll
        for (int k = 0; k < KADJ; ++k) {
            int d = (k >> 2) ^ g, j = k & 3;
            float sv = (d == 0) ? p[j] : (d == 1) ? q0[j] : (d == 2) ? q1[j] : q2[j];
            float alpha = __expf(sv - mx) * inv;
            u32 pk = *reinterpret_cast<const u32*>(
                adjb + k * 256 + ((((lane >> 2) ^ k)) << 4) + (lane & 3) * 4);
            float e0 = __builtin_bit_cast(float, pk << 16);
            float e1 = __builtin_bit_cast(float, pk & 0xFFFF0000u);
            a0 = fmaf(alpha, e0, a0);
            a1 = fmaf(alpha, e1, a1);
        }
        *reinterpret_cast<f32x2*>(att_out + (size_t)bn * DD + lane * 2) = f32x2{a0, a1};
    }
    #undef ISSUE
}

// ---- K2: out = relu([itm | att] @ w3) via MFMA; B-frags coalesced from w3f ----
__launch_bounds__(256)
__global__ void k_out(const float* __restrict__ itm, const float* att,
                      const __bf16* __restrict__ w3f, float* outp) {
    const int t = threadIdx.x;
    const int lane = t & 63;
    const int w = t >> 6;
    const int l = lane & 15, g = lane >> 4;
    const int R0 = blockIdx.x * 64 + w * 16;
    const int row = R0 + l;

    bf16x8 afr[8];
    const float* ip = itm + (size_t)row * DD;
    #pragma unroll
    for (int s = 0; s < 4; ++s) {
        int c = s * 32 + g * 8;
        f32x4 a0 = *reinterpret_cast<const f32x4*>(ip + c);
        f32x4 a1 = *reinterpret_cast<const f32x4*>(ip + c + 4);
        afr[s] = cvt8(a0, a1);
    }
    const float* ap = att + (size_t)row * DD;
    #pragma unroll
    for (int s = 0; s < 4; ++s) {
        int c = s * 32 + g * 8;
        f32x4 a0 = *reinterpret_cast<const f32x4*>(ap + c);
        f32x4 a1 = *reinterpret_cast<const f32x4*>(ap + c + 4);
        afr[4 + s] = cvt8(a0, a1);
    }

    f32x4 acc[8];
    #pragma unroll
    for (int n = 0; n < 8; ++n) acc[n] = f32x4{0.f, 0.f, 0.f, 0.f};
    #pragma unroll
    for (int s = 0; s < 8; ++s) {
        const __bf16* bp = w3f + ((size_t)s * 64 + lane) * 8;    // coalesced 1KB/wave
        #pragma unroll
        for (int n = 0; n < 8; ++n) {
            bf16x8 bfr = *reinterpret_cast<const bf16x8*>(bp + (size_t)n * 4096);
            acc[n] = __builtin_amdgcn_mfma_f32_16x16x32_bf16(afr[s], bfr, acc[n], 0, 0, 0);
        }
    }

    #pragma unroll
    for (int n = 0; n < 8; ++n) {
        #pragma unroll
        for (int j = 0; j < 4; ++j)
            outp[(size_t)(R0 + g * 4 + j) * DD + n * 16 + l] = fmaxf(acc[n][j], 0.f);
    }
}

extern "C" void kernel_launch(void* const* d_in, const int* in_sizes, int n_in,
                              void* d_out, int out_size, void* d_ws, size_t ws_size,
                              hipStream_t stream) {
    const float* itm = (const float*)d_in[1];
    const float* ave = (const float*)d_in[2];
    const float* adj = (const float*)d_in[3];
    const float* wgt = (const float*)d_in[4];
    const float* w1  = (const float*)d_in[5];
    const float* w2  = (const float*)d_in[6];
    const float* w3  = (const float*)d_in[7];
    float* outp = (float*)d_out;

    __bf16* w1f = (__bf16*)d_ws;                       // 32 KB, fragment-ordered
    __bf16* w3f = (__bf16*)((char*)d_ws + 32 * 1024);  // 64 KB, fragment-ordered

    k_prep<<<dim3(192), dim3(256), 0, stream>>>(w1, w3, w1f, w3f);
    k_att<<<dim3(BN_TOTAL / 32), dim3(256), 0, stream>>>(ave, adj, wgt, w1, w2, w1f, outp);
    k_out<<<dim3(BN_TOTAL / 64), dim3(256), 0, stream>>>(itm, outp, w3f, outp);
}